// Round 1
// baseline (218.843 us; speedup 1.0000x reference)
//
#include <hip/hip_runtime.h>

// Depthwise 41-tap separable gaussian blur of flow = noise*2-1.
// [16, 512, 512, 2] fp32, SAME zero padding.
//
// R5: two-pass split through d_ws mid buffer.
//   K1 vpass: vertical conv, no LDS / no barriers, 100% occupancy,
//             lane-dense float2 loads+stores, XCD-chunked block swizzle so
//             y-halo-sharing blocks hit the same XCD L2.
//   K2 hpass: horizontal conv, 8x256 tiles, 19KB LDS (8 blocks/CU),
//             dense staged loads -> sliding-window conv -> LDS transpose ->
//             full-line dense stores.
// Falls back to the previous fused kernel if ws_size < 33.5 MB.
#define NB   16
#define H    512
#define W    512
#define KW   41
#define HALO 20

// Raw gaussian taps exp(-d^2/50), d=-20..20; (1/sum)^2 folded into INV_S2.
constexpr float G[KW] = {
  0.0003354626f, 0.0007318024f, 0.0015338104f, 0.0030887172f,
  0.0059760229f, 0.0111089965f, 0.0198410947f, 0.0340474548f,
  0.0561347628f, 0.0889216176f, 0.1353352832f, 0.1978986990f,
  0.2780373005f, 0.3753110988f, 0.4867522560f, 0.6065306597f,
  0.7261490371f, 0.8352702114f, 0.9231163464f, 0.9801986733f,
  1.0f,
  0.9801986733f, 0.9231163464f, 0.8352702114f, 0.7261490371f,
  0.6065306597f, 0.4867522560f, 0.3753110988f, 0.2780373005f,
  0.1978986990f, 0.1353352832f, 0.0889216176f, 0.0561347628f,
  0.0340474548f, 0.0198410947f, 0.0111089965f, 0.0059760229f,
  0.0030887172f, 0.0015338104f, 0.0007318024f, 0.0003354626f
};

constexpr float gsum() { float s = 0.f; for (int i = 0; i < KW; ++i) s += G[i]; return s; }
constexpr float INV_S2 = 1.0f / (gsum() * gsum());

// ---------------------------------------------------------------------------
// K1: vertical 41-tap conv on flow = noise*2-1, writes raw vertical sums to
// mid. Thread = one x column (both channels as float2), V_PV output rows in
// registers. 56 dense 512B wave-loads per 16 output rows; zero LDS.
// ---------------------------------------------------------------------------
#define V_PV   16
#define V_ROWS (V_PV + KW - 1)   // 56

__global__ __launch_bounds__(256, 8)
void vpass_kernel(const float* __restrict__ noise, float* __restrict__ mid) {
    const int tid = threadIdx.x;

    // grid = (2, 32, 16) -> 1024 blocks. Bijective XCD chunk swizzle:
    // physical id p dispatches to XCD p%8; logical work (p%8)*128 + p/8 gives
    // each XCD a contiguous slab (2 full images = 4MB = one XCD L2), so the
    // 40-row y-halo re-reads hit the local L2 instead of HBM.
    int id = blockIdx.x + 2 * (blockIdx.y + 32 * blockIdx.z);
    id = ((id & 7) << 7) | (id >> 3);          // 1024/8 = 128 per XCD
    const int lx = id & 1;                     // 2 x-blocks of 256 cols
    const int ly = (id >> 1) & 31;             // 32 y-blocks of 16 rows
    const int lb = id >> 6;                    // 16 batches

    const int x  = lx * 256 + tid;             // 0..511, lane-dense
    const int y0 = ly * V_PV;

    const float* __restrict__ src = noise + ((size_t)lb * H * W + x) * 2;
    float*       __restrict__ dst = mid   + (((size_t)lb * H + y0) * W + x) * 2;

    float2 acc[V_PV];
    #pragma unroll
    for (int p = 0; p < V_PV; ++p) acc[p] = make_float2(0.f, 0.f);

    const int ysb = y0 - HALO;
    #pragma unroll
    for (int j = 0; j < V_ROWS; ++j) {         // 56 rows
        const int ys = ysb + j;
        const int cy = min(max(ys, 0), H - 1); // clamped (always-legal) address
        const float a  = (ys == cy) ? 2.0f : 0.0f;   // zero-pad via select
        const float bb = (ys == cy) ? -1.0f : 0.0f;
        const float2 u = *(const float2*)(src + (size_t)cy * (W * 2));
        float2 v;
        v.x = __builtin_fmaf(u.x, a, bb);
        v.y = __builtin_fmaf(u.y, a, bb);
        #pragma unroll
        for (int p = 0; p < V_PV; ++p) {
            const int t = j - p;               // compile-time after unroll
            if (t >= 0 && t < KW) {
                acc[p].x = __builtin_fmaf(G[t], v.x, acc[p].x);
                acc[p].y = __builtin_fmaf(G[t], v.y, acc[p].y);
            }
        }
    }
    #pragma unroll
    for (int p = 0; p < V_PV; ++p)             // lane-dense 512B store bursts
        *(float2*)(dst + (size_t)p * (W * 2)) = acc[p];
}

// ---------------------------------------------------------------------------
// K2: horizontal 41-tap conv from mid, scaled by INV_S2, writes out.
// Tile = 8 rows x 256 cols, staged with x-halo in 19KB LDS (8 blocks/CU).
// Conv thread = (row, 8-col group) sliding window; results round-trip
// through an aliased LDS region so global stores are lane-dense full lines.
// ---------------------------------------------------------------------------
#define HX   256                 // output cols per block
#define HR   8                   // rows per block
#define HIN  (HX + 2 * HALO)     // 296 staged cols
#define HSTR 297                 // stage row stride (float2)
#define HOSTR 257                // out-stage row stride (float2)
#define HPX  8                   // outputs per thread

__global__ __launch_bounds__(256, 8)
void hpass_kernel(const float* __restrict__ mid, float* __restrict__ out) {
    __shared__ float2 smem[HR * HSTR];   // 2376 float2 = 19008 B

    const int tid = threadIdx.x;
    const int x0  = blockIdx.x * HX;
    const int y0  = blockIdx.y * HR;
    const int b   = blockIdx.z;

    const float* __restrict__ srcb = mid + ((size_t)b * H + y0) * (W * 2);

    // stage 8 x 296 float2 (x-halo, zero-padded at image edges), dense rows
    #pragma unroll
    for (int k = 0; k < 10; ++k) {
        const int flat = tid + k * 256;
        if (flat < HR * HIN) {
            const int row = flat / HIN;        // const divide -> magic mul
            const int c   = flat - row * HIN;
            const int gx  = x0 + c - HALO;
            float2 v = make_float2(0.f, 0.f);
            if ((unsigned)gx < W)
                v = *(const float2*)(srcb + (size_t)row * (W * 2) + gx * 2);
            smem[row * HSTR + c] = v;
        }
    }
    __syncthreads();

    // sliding-window conv: 48 LDS reads per 8 outputs
    const int y  = tid & 7;
    const int xg = tid >> 3;                   // 0..31, HPX cols each
    float2 facc[HPX];
    #pragma unroll
    for (int p = 0; p < HPX; ++p) facc[p] = make_float2(0.f, 0.f);
    #pragma unroll
    for (int j = 0; j < HPX + KW - 1; ++j) {   // 48
        const float2 v = smem[y * HSTR + xg * HPX + j];
        #pragma unroll
        for (int p = 0; p < HPX; ++p) {
            const int t = j - p;
            if (t >= 0 && t < KW) {
                facc[p].x = __builtin_fmaf(G[t], v.x, facc[p].x);
                facc[p].y = __builtin_fmaf(G[t], v.y, facc[p].y);
            }
        }
    }
    __syncthreads();   // all stage reads done; safe to overwrite aliased region

    #pragma unroll
    for (int p = 0; p < HPX; ++p) {
        float2 r;
        r.x = facc[p].x * INV_S2;
        r.y = facc[p].y * INV_S2;
        smem[y * HOSTR + xg * HPX + p] = r;    // out-stage aliases stage region
    }
    __syncthreads();

    // lane-dense full-line stores: per k one full 256-col row segment (2KB)
    float* __restrict__ ob = out + (((size_t)b * H + y0) * W + x0) * 2;
    #pragma unroll
    for (int k = 0; k < 8; ++k) {
        const int flat = tid + k * 256;
        const int row  = flat >> 8;
        const int c    = flat & 255;
        *(float2*)(ob + (size_t)row * (W * 2) + c * 2) = smem[row * HOSTR + c];
    }
}

// ---------------------------------------------------------------------------
// Fallback: previous fused kernel (used only if ws_size is too small).
// ---------------------------------------------------------------------------
#define TX   88
#define TY   32
#define IN_W 128
#define PVV  16
#define PX   11
#define MSTR 129
#define OSTR 89
#define SMEM_F2 (TY * MSTR)

__global__ __launch_bounds__(256, 4)
void randflow_blur_kernel(const float* __restrict__ noise, float* __restrict__ out) {
    __shared__ float2 smem[SMEM_F2];

    const int tid = threadIdx.x;
    const int bx  = blockIdx.x;
    const int tx0 = bx * TX;
    const int ty0 = blockIdx.y * TY;
    const int b   = blockIdx.z;
    const float* __restrict__ src = noise + (size_t)b * (H * W * 2);

    {
        const int sx  = tid & 127;
        const int yg  = tid >> 7;
        const int gx  = tx0 + sx - HALO;
        const int cgx = min(max(gx, 0), W - 1);
        const float sa = (gx == cgx) ? 2.0f : 0.0f;
        const float sb = (gx == cgx) ? -1.0f : 0.0f;
        const int  ysb = ty0 + yg * PVV - HALO;
        const float* __restrict__ colp = src + 2 * cgx;

        float2 acc[PVV];
        #pragma unroll
        for (int p = 0; p < PVV; ++p) acc[p] = make_float2(0.f, 0.f);

        #pragma unroll
        for (int j = 0; j < PVV + KW - 1; ++j) {
            const int ys = ysb + j;
            const int cy = min(max(ys, 0), H - 1);
            const float a  = (ys == cy) ? sa : 0.0f;
            const float bb = (ys == cy) ? sb : 0.0f;
            const float2 u = *(const float2*)(colp + (size_t)cy * (W * 2));
            float2 v;
            v.x = __builtin_fmaf(u.x, a, bb);
            v.y = __builtin_fmaf(u.y, a, bb);
            #pragma unroll
            for (int p = 0; p < PVV; ++p) {
                const int t = j - p;
                if (t >= 0 && t < KW) {
                    acc[p].x = __builtin_fmaf(G[t], v.x, acc[p].x);
                    acc[p].y = __builtin_fmaf(G[t], v.y, acc[p].y);
                }
            }
        }
        #pragma unroll
        for (int p = 0; p < PVV; ++p)
            smem[(yg * PVV + p) * MSTR + sx] = acc[p];
    }
    __syncthreads();

    const int y  = tid & 31;
    const int xg = tid >> 5;
    const int x0 = xg * PX;
    float2 facc[PX];
    {
        #pragma unroll
        for (int p = 0; p < PX; ++p) facc[p] = make_float2(0.f, 0.f);
        #pragma unroll
        for (int j = 0; j < PX + KW - 1; ++j) {
            const float2 v = smem[y * MSTR + x0 + j];
            #pragma unroll
            for (int p = 0; p < PX; ++p) {
                const int t = j - p;
                if (t >= 0 && t < KW) {
                    facc[p].x = __builtin_fmaf(G[t], v.x, facc[p].x);
                    facc[p].y = __builtin_fmaf(G[t], v.y, facc[p].y);
                }
            }
        }
    }
    __syncthreads();

    #pragma unroll
    for (int p = 0; p < PX; ++p) {
        float2 r;
        r.x = facc[p].x * INV_S2;
        r.y = facc[p].y * INV_S2;
        smem[y * OSTR + x0 + p] = r;
    }
    __syncthreads();

    #pragma unroll
    for (int p = 0; p < PX; ++p) {
        const int flat = p * 256 + tid;
        const int ry = flat / TX;
        const int rx = flat - ry * TX;
        const int xo = tx0 + rx;
        if (xo < W) {
            const int yo = ty0 + ry;
            *(float2*)(out + (((size_t)b * H + yo) * W + xo) * 2) = smem[ry * OSTR + rx];
        }
    }
}

extern "C" void kernel_launch(void* const* d_in, const int* in_sizes, int n_in,
                              void* d_out, int out_size, void* d_ws, size_t ws_size,
                              hipStream_t stream) {
    // d_in[0] = inputs [16,512,512,1]  -- UNUSED by the reference
    // d_in[1] = rand_noise [16,512,512,2] fp32
    const float* noise = (const float*)d_in[1];
    float* out = (float*)d_out;

    const size_t mid_bytes = (size_t)NB * H * W * 2 * sizeof(float);  // 33.5 MB
    if (d_ws != nullptr && ws_size >= mid_bytes) {
        float* mid = (float*)d_ws;
        vpass_kernel<<<dim3(2, 32, NB), dim3(256), 0, stream>>>(noise, mid);
        hpass_kernel<<<dim3(2, H / HR, NB), dim3(256), 0, stream>>>(mid, out);
    } else {
        dim3 grid((W + TX - 1) / TX, H / TY, NB);
        randflow_blur_kernel<<<grid, dim3(256), 0, stream>>>(noise, out);
    }
}

// Round 2
// 109.848 us; speedup vs baseline: 1.9922x; 1.9922x over previous
//
#include <hip/hip_runtime.h>

// Depthwise 41-tap separable gaussian blur of flow = noise*2-1.
// [16, 512, 512, 2] fp32, SAME zero padding.
//
// R6: two-pass split through d_ws mid buffer (R5 structure), with the vpass
// register-spill fixed: __launch_bounds__(256,8) capped the allocator at 64
// VGPRs, which spilled the 32-VGPR accumulator array to scratch (measured:
// VGPR_Count=32, WRITE_SIZE 6x mid size, VALUBusy 4.8%, 135us). Relaxed to
// (256,4) -> 128-VGPR cap, no spill (fused-kernel phase 1 measured 64 VGPRs
// at this cap with the identical accumulator structure).
//   K1 vpass: vertical conv, no LDS / no barriers, lane-dense float2
//             loads+stores, XCD-chunked block swizzle so y-halo-sharing
//             blocks hit the same XCD L2.
//   K2 hpass: horizontal conv, 8x256 tiles, 19KB LDS (8 blocks/CU),
//             dense staged loads -> sliding-window conv -> LDS transpose ->
//             full-line dense stores. (~9us, near traffic floor.)
// Falls back to the fused kernel if ws_size < 33.5 MB.
#define NB   16
#define H    512
#define W    512
#define KW   41
#define HALO 20

// Raw gaussian taps exp(-d^2/50), d=-20..20; (1/sum)^2 folded into INV_S2.
constexpr float G[KW] = {
  0.0003354626f, 0.0007318024f, 0.0015338104f, 0.0030887172f,
  0.0059760229f, 0.0111089965f, 0.0198410947f, 0.0340474548f,
  0.0561347628f, 0.0889216176f, 0.1353352832f, 0.1978986990f,
  0.2780373005f, 0.3753110988f, 0.4867522560f, 0.6065306597f,
  0.7261490371f, 0.8352702114f, 0.9231163464f, 0.9801986733f,
  1.0f,
  0.9801986733f, 0.9231163464f, 0.8352702114f, 0.7261490371f,
  0.6065306597f, 0.4867522560f, 0.3753110988f, 0.2780373005f,
  0.1978986990f, 0.1353352832f, 0.0889216176f, 0.0561347628f,
  0.0340474548f, 0.0198410947f, 0.0111089965f, 0.0059760229f,
  0.0030887172f, 0.0015338104f, 0.0007318024f, 0.0003354626f
};

constexpr float gsum() { float s = 0.f; for (int i = 0; i < KW; ++i) s += G[i]; return s; }
constexpr float INV_S2 = 1.0f / (gsum() * gsum());

// ---------------------------------------------------------------------------
// K1: vertical 41-tap conv on flow = noise*2-1, writes raw vertical sums to
// mid. Thread = one x column (both channels as float2), V_PV output rows in
// registers. 56 dense 512B wave-loads per 16 output rows; zero LDS.
// ---------------------------------------------------------------------------
#define V_PV   16
#define V_ROWS (V_PV + KW - 1)   // 56

__global__ __launch_bounds__(256, 4)   // 128-VGPR cap: acc[16] float2 must stay in regs
void vpass_kernel(const float* __restrict__ noise, float* __restrict__ mid) {
    const int tid = threadIdx.x;

    // grid = (2, 32, 16) -> 1024 blocks. Bijective XCD chunk swizzle:
    // physical id p dispatches to XCD p%8; logical work (p%8)*128 + p/8 gives
    // each XCD a contiguous slab (2 full images = 4MB = one XCD L2), so the
    // 40-row y-halo re-reads hit the local L2 instead of HBM.
    int id = blockIdx.x + 2 * (blockIdx.y + 32 * blockIdx.z);
    id = ((id & 7) << 7) | (id >> 3);          // 1024/8 = 128 per XCD
    const int lx = id & 1;                     // 2 x-blocks of 256 cols
    const int ly = (id >> 1) & 31;             // 32 y-blocks of 16 rows
    const int lb = id >> 6;                    // 16 batches

    const int x  = lx * 256 + tid;             // 0..511, lane-dense
    const int y0 = ly * V_PV;

    const float* __restrict__ src = noise + ((size_t)lb * H * W + x) * 2;
    float*       __restrict__ dst = mid   + (((size_t)lb * H + y0) * W + x) * 2;

    float2 acc[V_PV];
    #pragma unroll
    for (int p = 0; p < V_PV; ++p) acc[p] = make_float2(0.f, 0.f);

    const int ysb = y0 - HALO;
    #pragma unroll
    for (int j = 0; j < V_ROWS; ++j) {         // 56 rows
        const int ys = ysb + j;
        const int cy = min(max(ys, 0), H - 1); // clamped (always-legal) address
        const float a  = (ys == cy) ? 2.0f : 0.0f;   // zero-pad via select
        const float bb = (ys == cy) ? -1.0f : 0.0f;
        const float2 u = *(const float2*)(src + (size_t)cy * (W * 2));
        float2 v;
        v.x = __builtin_fmaf(u.x, a, bb);
        v.y = __builtin_fmaf(u.y, a, bb);
        #pragma unroll
        for (int p = 0; p < V_PV; ++p) {
            const int t = j - p;               // compile-time after unroll
            if (t >= 0 && t < KW) {
                acc[p].x = __builtin_fmaf(G[t], v.x, acc[p].x);
                acc[p].y = __builtin_fmaf(G[t], v.y, acc[p].y);
            }
        }
    }
    #pragma unroll
    for (int p = 0; p < V_PV; ++p)             // lane-dense 512B store bursts
        *(float2*)(dst + (size_t)p * (W * 2)) = acc[p];
}

// ---------------------------------------------------------------------------
// K2: horizontal 41-tap conv from mid, scaled by INV_S2, writes out.
// Tile = 8 rows x 256 cols, staged with x-halo in 19KB LDS (8 blocks/CU).
// Conv thread = (row, 8-col group) sliding window; results round-trip
// through an aliased LDS region so global stores are lane-dense full lines.
// ---------------------------------------------------------------------------
#define HX   256                 // output cols per block
#define HR   8                   // rows per block
#define HIN  (HX + 2 * HALO)     // 296 staged cols
#define HSTR 297                 // stage row stride (float2)
#define HOSTR 257                // out-stage row stride (float2)
#define HPX  8                   // outputs per thread

__global__ __launch_bounds__(256, 8)
void hpass_kernel(const float* __restrict__ mid, float* __restrict__ out) {
    __shared__ float2 smem[HR * HSTR];   // 2376 float2 = 19008 B

    const int tid = threadIdx.x;
    const int x0  = blockIdx.x * HX;
    const int y0  = blockIdx.y * HR;
    const int b   = blockIdx.z;

    const float* __restrict__ srcb = mid + ((size_t)b * H + y0) * (W * 2);

    // stage 8 x 296 float2 (x-halo, zero-padded at image edges), dense rows
    #pragma unroll
    for (int k = 0; k < 10; ++k) {
        const int flat = tid + k * 256;
        if (flat < HR * HIN) {
            const int row = flat / HIN;        // const divide -> magic mul
            const int c   = flat - row * HIN;
            const int gx  = x0 + c - HALO;
            float2 v = make_float2(0.f, 0.f);
            if ((unsigned)gx < W)
                v = *(const float2*)(srcb + (size_t)row * (W * 2) + gx * 2);
            smem[row * HSTR + c] = v;
        }
    }
    __syncthreads();

    // sliding-window conv: 48 LDS reads per 8 outputs
    const int y  = tid & 7;
    const int xg = tid >> 3;                   // 0..31, HPX cols each
    float2 facc[HPX];
    #pragma unroll
    for (int p = 0; p < HPX; ++p) facc[p] = make_float2(0.f, 0.f);
    #pragma unroll
    for (int j = 0; j < HPX + KW - 1; ++j) {   // 48
        const float2 v = smem[y * HSTR + xg * HPX + j];
        #pragma unroll
        for (int p = 0; p < HPX; ++p) {
            const int t = j - p;
            if (t >= 0 && t < KW) {
                facc[p].x = __builtin_fmaf(G[t], v.x, facc[p].x);
                facc[p].y = __builtin_fmaf(G[t], v.y, facc[p].y);
            }
        }
    }
    __syncthreads();   // all stage reads done; safe to overwrite aliased region

    #pragma unroll
    for (int p = 0; p < HPX; ++p) {
        float2 r;
        r.x = facc[p].x * INV_S2;
        r.y = facc[p].y * INV_S2;
        smem[y * HOSTR + xg * HPX + p] = r;    // out-stage aliases stage region
    }
    __syncthreads();

    // lane-dense full-line stores: per k one full 256-col row segment (2KB)
    float* __restrict__ ob = out + (((size_t)b * H + y0) * W + x0) * 2;
    #pragma unroll
    for (int k = 0; k < 8; ++k) {
        const int flat = tid + k * 256;
        const int row  = flat >> 8;
        const int c    = flat & 255;
        *(float2*)(ob + (size_t)row * (W * 2) + c * 2) = smem[row * HOSTR + c];
    }
}

// ---------------------------------------------------------------------------
// Fallback: previous fused kernel (used only if ws_size is too small).
// ---------------------------------------------------------------------------
#define TX   88
#define TY   32
#define IN_W 128
#define PVV  16
#define PX   11
#define MSTR 129
#define OSTR 89
#define SMEM_F2 (TY * MSTR)

__global__ __launch_bounds__(256, 4)
void randflow_blur_kernel(const float* __restrict__ noise, float* __restrict__ out) {
    __shared__ float2 smem[SMEM_F2];

    const int tid = threadIdx.x;
    const int bx  = blockIdx.x;
    const int tx0 = bx * TX;
    const int ty0 = blockIdx.y * TY;
    const int b   = blockIdx.z;
    const float* __restrict__ src = noise + (size_t)b * (H * W * 2);

    {
        const int sx  = tid & 127;
        const int yg  = tid >> 7;
        const int gx  = tx0 + sx - HALO;
        const int cgx = min(max(gx, 0), W - 1);
        const float sa = (gx == cgx) ? 2.0f : 0.0f;
        const float sb = (gx == cgx) ? -1.0f : 0.0f;
        const int  ysb = ty0 + yg * PVV - HALO;
        const float* __restrict__ colp = src + 2 * cgx;

        float2 acc[PVV];
        #pragma unroll
        for (int p = 0; p < PVV; ++p) acc[p] = make_float2(0.f, 0.f);

        #pragma unroll
        for (int j = 0; j < PVV + KW - 1; ++j) {
            const int ys = ysb + j;
            const int cy = min(max(ys, 0), H - 1);
            const float a  = (ys == cy) ? sa : 0.0f;
            const float bb = (ys == cy) ? sb : 0.0f;
            const float2 u = *(const float2*)(colp + (size_t)cy * (W * 2));
            float2 v;
            v.x = __builtin_fmaf(u.x, a, bb);
            v.y = __builtin_fmaf(u.y, a, bb);
            #pragma unroll
            for (int p = 0; p < PVV; ++p) {
                const int t = j - p;
                if (t >= 0 && t < KW) {
                    acc[p].x = __builtin_fmaf(G[t], v.x, acc[p].x);
                    acc[p].y = __builtin_fmaf(G[t], v.y, acc[p].y);
                }
            }
        }
        #pragma unroll
        for (int p = 0; p < PVV; ++p)
            smem[(yg * PVV + p) * MSTR + sx] = acc[p];
    }
    __syncthreads();

    const int y  = tid & 31;
    const int xg = tid >> 5;
    const int x0 = xg * PX;
    float2 facc[PX];
    {
        #pragma unroll
        for (int p = 0; p < PX; ++p) facc[p] = make_float2(0.f, 0.f);
        #pragma unroll
        for (int j = 0; j < PX + KW - 1; ++j) {
            const float2 v = smem[y * MSTR + x0 + j];
            #pragma unroll
            for (int p = 0; p < PX; ++p) {
                const int t = j - p;
                if (t >= 0 && t < KW) {
                    facc[p].x = __builtin_fmaf(G[t], v.x, facc[p].x);
                    facc[p].y = __builtin_fmaf(G[t], v.y, facc[p].y);
                }
            }
        }
    }
    __syncthreads();

    #pragma unroll
    for (int p = 0; p < PX; ++p) {
        float2 r;
        r.x = facc[p].x * INV_S2;
        r.y = facc[p].y * INV_S2;
        smem[y * OSTR + x0 + p] = r;
    }
    __syncthreads();

    #pragma unroll
    for (int p = 0; p < PX; ++p) {
        const int flat = p * 256 + tid;
        const int ry = flat / TX;
        const int rx = flat - ry * TX;
        const int xo = tx0 + rx;
        if (xo < W) {
            const int yo = ty0 + ry;
            *(float2*)(out + (((size_t)b * H + yo) * W + xo) * 2) = smem[ry * OSTR + rx];
        }
    }
}

extern "C" void kernel_launch(void* const* d_in, const int* in_sizes, int n_in,
                              void* d_out, int out_size, void* d_ws, size_t ws_size,
                              hipStream_t stream) {
    // d_in[0] = inputs [16,512,512,1]  -- UNUSED by the reference
    // d_in[1] = rand_noise [16,512,512,2] fp32
    const float* noise = (const float*)d_in[1];
    float* out = (float*)d_out;

    const size_t mid_bytes = (size_t)NB * H * W * 2 * sizeof(float);  // 33.5 MB
    if (d_ws != nullptr && ws_size >= mid_bytes) {
        float* mid = (float*)d_ws;
        vpass_kernel<<<dim3(2, 32, NB), dim3(256), 0, stream>>>(noise, mid);
        hpass_kernel<<<dim3(2, H / HR, NB), dim3(256), 0, stream>>>(mid, out);
    } else {
        dim3 grid((W + TX - 1) / TX, H / TY, NB);
        randflow_blur_kernel<<<grid, dim3(256), 0, stream>>>(noise, out);
    }
}

// Round 3
// 108.475 us; speedup vs baseline: 2.0175x; 1.0127x over previous
//
#include <hip/hip_runtime.h>

// Depthwise 41-tap separable gaussian blur of flow = noise*2-1.
// [16, 512, 512, 2] fp32, SAME zero padding.
//
// R7: single fused full-width kernel. R6's two-pass paid a 67 MB mid
// round-trip (134 MB total vs 67 MB compulsory) plus a second launch.
// A block spanning the full 512-col width has NO horizontal halo (the
// x-window at block edges is the actual image boundary -> zero-pad held
// in LDS), so the vertical-conv intermediate never touches global memory.
//   phase 1: vertical 41-tap conv, thread = one x column (dense float2
//            loads), 16 output rows in registers -> LDS (zero-padded rows).
//   phase 2: horizontal 41-tap conv from LDS, sliding window, 16 cols/thread.
//   phase 3: results -> aliased LDS region -> 16 dense full-row 4KB stores.
// 512 threads, 70.8 KB LDS -> 2 blocks/CU, grid 512 = exactly 2/CU.
// XCD-chunk swizzle: each XCD owns 2 contiguous images (64 co-resident
// blocks) so the 40-row vertical halo re-reads hit the local 4MB L2.
#define NB   16
#define H    512
#define W    512
#define KW   41
#define HALO 20

#define FTY   16                  // output rows per block
#define FROWS (FTY + KW - 1)      // 56 input rows loaded
#define PADW  (W + 2 * HALO)      // 552 padded cols in LDS
#define SSTR  553                 // mid row stride (float2): 552 + 1 pad
#define OSTR  513                 // out-stage row stride (float2)
#define HPX   16                  // horizontal outputs per thread

// Raw gaussian taps exp(-d^2/50), d=-20..20; (1/sum)^2 folded into INV_S2.
constexpr float G[KW] = {
  0.0003354626f, 0.0007318024f, 0.0015338104f, 0.0030887172f,
  0.0059760229f, 0.0111089965f, 0.0198410947f, 0.0340474548f,
  0.0561347628f, 0.0889216176f, 0.1353352832f, 0.1978986990f,
  0.2780373005f, 0.3753110988f, 0.4867522560f, 0.6065306597f,
  0.7261490371f, 0.8352702114f, 0.9231163464f, 0.9801986733f,
  1.0f,
  0.9801986733f, 0.9231163464f, 0.8352702114f, 0.7261490371f,
  0.6065306597f, 0.4867522560f, 0.3753110988f, 0.2780373005f,
  0.1978986990f, 0.1353352832f, 0.0889216176f, 0.0561347628f,
  0.0340474548f, 0.0198410947f, 0.0111089965f, 0.0059760229f,
  0.0030887172f, 0.0015338104f, 0.0007318024f, 0.0003354626f
};

constexpr float gsum() { float s = 0.f; for (int i = 0; i < KW; ++i) s += G[i]; return s; }
constexpr float INV_S2 = 1.0f / (gsum() * gsum());

__global__ __launch_bounds__(512, 4)   // 128-VGPR cap: acc[16] float2 stays in regs
void randflow_fused_kernel(const float* __restrict__ noise, float* __restrict__ out) {
    __shared__ float2 smem[FTY * SSTR];   // 8848 float2 = 70784 B -> 2 blocks/CU

    const int tid = threadIdx.x;          // 0..511 = x column

    // grid (32, 16) -> 512 blocks, physical id = bx + 32*by dispatches to
    // XCD id%8. Bijective chunk swizzle: sid = (id&7)*64 + id/8 gives each
    // XCD 64 consecutive (y-block, batch) slots = 2 whole images = 4.2 MB,
    // all co-resident (2 blocks/CU x 32 CU/XCD) -> y-halo re-reads L2-hit.
    int id = blockIdx.x + 32 * blockIdx.y;
    id = ((id & 7) << 6) | (id >> 3);
    const int ly = id & 31;               // 32 y-blocks of 16 rows
    const int lb = id >> 5;               // 16 batches
    const int y0 = ly * FTY;

    // zero the 20-col left/right borders of all 16 LDS rows (image zero-pad)
    #pragma unroll
    for (int k = 0; k < 2; ++k) {
        const int flat = tid + k * 512;
        if (flat < FTY * 2 * HALO) {              // 640
            const int row = flat / 40;            // const divide -> magic mul
            const int c   = flat - row * 40;
            const int col = (c < HALO) ? c : (c + W);   // [0,20) U [532,552)
            smem[row * SSTR + col] = make_float2(0.f, 0.f);
        }
    }

    // ---- phase 1: vertical 41-tap conv on flow = noise*2-1.
    // Thread = column tid, both channels as float2; 56 dense 4KB wave-row
    // loads; zero-pad in y via select on clamped (always-legal) addresses.
    {
        const float* __restrict__ src = noise + ((size_t)lb * H * W + tid) * 2;
        float2 acc[FTY];
        #pragma unroll
        for (int p = 0; p < FTY; ++p) acc[p] = make_float2(0.f, 0.f);

        const int ysb = y0 - HALO;
        #pragma unroll
        for (int j = 0; j < FROWS; ++j) {         // 56 rows
            const int ys = ysb + j;
            const int cy = min(max(ys, 0), H - 1);
            const float a  = (ys == cy) ? 2.0f : 0.0f;   // y-validity select
            const float bb = (ys == cy) ? -1.0f : 0.0f;
            const float2 u = *(const float2*)(src + (size_t)cy * (W * 2));
            float2 v;
            v.x = __builtin_fmaf(u.x, a, bb);
            v.y = __builtin_fmaf(u.y, a, bb);
            #pragma unroll
            for (int p = 0; p < FTY; ++p) {
                const int t = j - p;              // compile-time after unroll
                if (t >= 0 && t < KW) {
                    acc[p].x = __builtin_fmaf(G[t], v.x, acc[p].x);
                    acc[p].y = __builtin_fmaf(G[t], v.y, acc[p].y);
                }
            }
        }
        #pragma unroll
        for (int p = 0; p < FTY; ++p)             // lanes dense along x
            smem[p * SSTR + HALO + tid] = acc[p];
    }
    __syncthreads();

    // ---- phase 2: horizontal 41-tap conv in LDS, sliding window.
    // Thread = (row y, 16-col group xg); 56 reads per 16 outputs.
    // SSTR=553 -> uniform 4 lanes/bank-pair = wave64 8-byte floor.
    const int y  = tid & 15;
    const int xg = tid >> 4;                      // 0..31
    const int x0 = xg * HPX;
    float2 facc[HPX];
    {
        #pragma unroll
        for (int p = 0; p < HPX; ++p) facc[p] = make_float2(0.f, 0.f);
        #pragma unroll
        for (int j = 0; j < HPX + KW - 1; ++j) {  // 56 padded cols x0..x0+55
            const float2 v = smem[y * SSTR + x0 + j];
            #pragma unroll
            for (int p = 0; p < HPX; ++p) {
                const int t = j - p;
                if (t >= 0 && t < KW) {
                    facc[p].x = __builtin_fmaf(G[t], v.x, facc[p].x);
                    facc[p].y = __builtin_fmaf(G[t], v.y, facc[p].y);
                }
            }
        }
    }
    __syncthreads();   // all phase-2 reads done; safe to overwrite alias

    // out-stage (aliases smem): scaled results, transpose-friendly layout
    #pragma unroll
    for (int p = 0; p < HPX; ++p) {
        float2 r;
        r.x = facc[p].x * INV_S2;
        r.y = facc[p].y * INV_S2;
        smem[y * OSTR + x0 + p] = r;
    }
    __syncthreads();

    // ---- phase 3: 16 dense full-row 4KB stores, lanes dense along x.
    float* __restrict__ ob = out + (((size_t)lb * H + y0) * W) * 2;
    #pragma unroll
    for (int k = 0; k < FTY; ++k)
        *(float2*)(ob + (size_t)k * (W * 2) + tid * 2) = smem[k * OSTR + tid];
}

extern "C" void kernel_launch(void* const* d_in, const int* in_sizes, int n_in,
                              void* d_out, int out_size, void* d_ws, size_t ws_size,
                              hipStream_t stream) {
    // d_in[0] = inputs [16,512,512,1]  -- UNUSED by the reference
    // d_in[1] = rand_noise [16,512,512,2] fp32
    const float* noise = (const float*)d_in[1];
    float* out = (float*)d_out;

    randflow_fused_kernel<<<dim3(H / FTY, NB), dim3(512), 0, stream>>>(noise, out);
}